// Round 4
// baseline (462.378 us; speedup 1.0000x reference)
//
#include <hip/hip_runtime.h>

#define BATCH 8
#define CIN   64
#define COUT  64
#define HDIM  128
#define WDIM  128
#define HW    (HDIM * WDIM)
#define KK    9
#define QC    16          // channels per pipeline step
#define NSTEP (KK * 4)    // 9 taps x 4 channel-groups = 36

// ---------------------------------------------------------------------------
// Kernel W: transpose weight [oc][c][k] -> Wt [k][c][oc]
// ---------------------------------------------------------------------------
__global__ __launch_bounds__(256) void transpose_w_kernel(
    const float* __restrict__ w, float* __restrict__ wt)
{
    const int i = blockIdx.x * 256 + threadIdx.x;   // 0 .. 64*64*9-1
    if (i < COUT * CIN * KK) {
        const int k = i / (CIN * COUT);
        const int r = i - k * (CIN * COUT);
        const int c = r >> 6;
        const int oc = r & 63;
        wt[i] = w[((size_t)oc * CIN + c) * KK + k];
    }
}

// ---------------------------------------------------------------------------
// Kernel A: offset conv, flattened grid with XCD-aligned batch (blk&7 == b
// == XCD id => each XCD's L2 holds exactly one batch's x, 4.2 MB).
// z-parity folded into the linear index: par selects dy/py vs dx/px.
// ---------------------------------------------------------------------------
__global__ __launch_bounds__(256) void offset_conv_kernel(
    const float* __restrict__ x,
    const float* __restrict__ ow,   // [18][64][3][3]
    const float* __restrict__ ob,   // [18]
    float* __restrict__ py,         // [B][KK][HW]
    float* __restrict__ px)
{
    const int tid = threadIdx.x;
    const int lin = blockIdx.x;          // 0..1023
    const int b   = lin & 7;             // XCD-aligned batch
    const int par = (lin >> 3) & 1;      // 0: dy/py, 1: dx/px
    const int pixel = (lin >> 4) * 256 + tid;
    const int h = pixel >> 7;
    const int w = pixel & 127;

    float acc[9];
#pragma unroll
    for (int i = 0; i < 9; ++i) acc[i] = ob[2 * i + par];

    const float* xb = x + (size_t)b * CIN * HW;

    auto loadx = [&](float* xv, int c) {
        const float* xc = xb + c * HW;
#pragma unroll
        for (int dh = 0; dh < 3; ++dh) {
            const int y = h + dh - 1;
            const bool vy = (unsigned)y < (unsigned)HDIM;
#pragma unroll
            for (int dw = 0; dw < 3; ++dw) {
                const int xw = w + dw - 1;
                const bool vx = (unsigned)xw < (unsigned)WDIM;
                float v = 0.0f;
                if (vy && vx) v = xc[y * WDIM + xw];
                xv[dh * 3 + dw] = v;
            }
        }
    };

    float xva[9], xvb[9];
    loadx(xva, 0);
    for (int c = 0; c < CIN; c += 2) {
        loadx(xvb, c + 1);
#pragma unroll
        for (int i = 0; i < 9; ++i) {
            const float* wp = ow + ((size_t)(2 * i + par) * CIN + c) * 9;
#pragma unroll
            for (int t = 0; t < 9; ++t) acc[i] = fmaf(xva[t], wp[t], acc[i]);
        }
        if (c + 2 < CIN) loadx(xva, c + 2);
#pragma unroll
        for (int i = 0; i < 9; ++i) {
            const float* wp = ow + ((size_t)(2 * i + par) * CIN + (c + 1)) * 9;
#pragma unroll
            for (int t = 0; t < 9; ++t) acc[i] = fmaf(xvb[t], wp[t], acc[i]);
        }
    }

    float* dst = par ? px : py;
#pragma unroll
    for (int i = 0; i < 9; ++i) {
        const int ki = i / 3, kj = i % 3;
        const float base = par ? (float)(w - 1 + kj) : (float)(h - 1 + ki);
        dst[((size_t)b * KK + i) * HW + pixel] = base + acc[i];
    }
}

// ---------------------------------------------------------------------------
// Kernel B v4: fused sampling + implicit GEMM, software-pipelined.
// Grid 1024; batch = blk&7 (XCD-aligned => x gathers L2-resident).
// Block = 256 threads (4 waves), one output row: 128 px x 64 oc.
// Wave w owns 16 oc; lane owns 2 px -> acc[2][16].
// 36 steps of 16 channels; per step: issue next group's 32 scattered gathers
// (in-flight regs) -> GEMM current group (1024 issue-cycles, hides latency)
// -> blend + LDS write -> 1 barrier. W via wave-uniform s_loads (no LDS).
// ---------------------------------------------------------------------------
__global__ __launch_bounds__(256)
__attribute__((amdgpu_waves_per_eu(4, 4)))
void deform_main_kernel(
    const float* __restrict__ x,
    const float* __restrict__ wt,   // [k][c][oc]
    const float* __restrict__ py,
    const float* __restrict__ px,
    float* __restrict__ out)
{
    __shared__ float A_s[2][QC][WDIM];   // 16 KB

    const int tid = threadIdx.x;
    const int blk = blockIdx.x;
    const int b = blk & 7;               // XCD-aligned batch
    const int h = blk >> 3;              // 0..127
    const int lane = tid & 63;
    const int wid = __builtin_amdgcn_readfirstlane(tid >> 6);  // 0..3 uniform
    const int pix_g = tid & 127;         // gather pixel
    const int cgrp8 = (tid >> 7) * 8;    // 0 or 8: gather channel sub-group

    float acc[2][16];
#pragma unroll
    for (int i = 0; i < 2; ++i)
#pragma unroll
        for (int j = 0; j < 16; ++j) acc[i][j] = 0.0f;

    const char* xb = (const char*)(x + (size_t)b * CIN * HW);
    const float* pyb = py + (size_t)b * KK * HW + h * WDIM + pix_g;
    const float* pxb = px + (size_t)b * KK * HW + h * WDIM + pix_g;

    int   idb0, idb1, idb2, idb3;   // byte offsets of 4 bilinear corners
    float w0, w1, w2, w3;           // bilinear weights (validity folded in)
    auto compute_params = [&](float pyv_, float pxv_) {
        const float y0f = floorf(pyv_), x0f = floorf(pxv_);
        const float fy = pyv_ - y0f, fx = pxv_ - x0f;
        const int y0 = (int)y0f, x0 = (int)x0f;
        const int y1 = y0 + 1, x1 = x0 + 1;
        const bool vy0 = (unsigned)y0 < (unsigned)HDIM;
        const bool vy1 = (unsigned)y1 < (unsigned)HDIM;
        const bool vx0 = (unsigned)x0 < (unsigned)WDIM;
        const bool vx1 = (unsigned)x1 < (unsigned)WDIM;
        const int cy0 = min(max(y0, 0), HDIM - 1);
        const int cy1 = min(max(y1, 0), HDIM - 1);
        const int cx0 = min(max(x0, 0), WDIM - 1);
        const int cx1 = min(max(x1, 0), WDIM - 1);
        idb0 = (cy0 * WDIM + cx0) * 4;  idb1 = (cy0 * WDIM + cx1) * 4;
        idb2 = (cy1 * WDIM + cx0) * 4;  idb3 = (cy1 * WDIM + cx1) * 4;
        const float wy0 = 1.0f - fy, wy1 = fy;
        const float wx0 = 1.0f - fx, wx1 = fx;
        w0 = wy0 * wx0 * (float)(vy0 && vx0);
        w1 = wy0 * wx1 * (float)(vy0 && vx1);
        w2 = wy1 * wx0 * (float)(vy1 && vx0);
        w3 = wy1 * wx1 * (float)(vy1 && vx1);
    };

    // ---- prologue: params tap 0; stage channels 0..15 into buffer 0
    float pyv = pyb[0], pxv = pxb[0];
    compute_params(pyv, pxv);
    {
#pragma unroll
        for (int i = 0; i < 8; ++i) {
            const char* xc = xb + (size_t)(cgrp8 + i) * (HW * 4);
            float v = *(const float*)(xc + idb0) * w0;
            v = fmaf(*(const float*)(xc + idb1), w1, v);
            v = fmaf(*(const float*)(xc + idb2), w2, v);
            v = fmaf(*(const float*)(xc + idb3), w3, v);
            A_s[0][cgrp8 + i][pix_g] = v;
        }
    }
    __syncthreads();

    // ---- main pipelined loop: 36 steps of 16 channels
    for (int s = 0; s < NSTEP; ++s) {
        const int p = s & 1;
        const int sn = s + 1;
        const int tn = sn >> 2, qn = sn & 3;
        const bool hn = sn < NSTEP;

        // issue next group's 32 scattered gather loads (stay in flight)
        float g[32];
        if (hn) {
            if (qn == 0) compute_params(pyv, pxv);  // params for tap tn
            const char* xq = xb + (size_t)(qn * QC + cgrp8) * (HW * 4);
#pragma unroll
            for (int i = 0; i < 8; ++i) {
                const char* xc = xq + (size_t)i * (HW * 4);
                g[i * 4 + 0] = *(const float*)(xc + idb0);
                g[i * 4 + 1] = *(const float*)(xc + idb1);
                g[i * 4 + 2] = *(const float*)(xc + idb2);
                g[i * 4 + 3] = *(const float*)(xc + idb3);
            }
            if (qn == 1 && tn + 1 < KK) {   // prefetch next tap's positions
                pyv = pyb[(size_t)(tn + 1) * HW];
                pxv = pxb[(size_t)(tn + 1) * HW];
            }
        }

        // GEMM on current group: A from LDS (b64), W from scalar loads
        {
            const int ks = s >> 2, qs = s & 3;
            const float* wq = wt + ((size_t)ks * CIN + qs * QC) * COUT + wid * 16;
#pragma unroll
            for (int c = 0; c < QC; ++c) {
                const float2 a = *(const float2*)&A_s[p][c][lane * 2];
#pragma unroll
                for (int j = 0; j < 16; ++j) {
                    const float wv = wq[c * COUT + j];   // s_load (uniform)
                    acc[0][j] = fmaf(a.x, wv, acc[0][j]);
                    acc[1][j] = fmaf(a.y, wv, acc[1][j]);
                }
            }
        }

        // blend gathered values, write into the other buffer
        if (hn) {
#pragma unroll
            for (int i = 0; i < 8; ++i) {
                float v = g[i * 4 + 0] * w0;
                v = fmaf(g[i * 4 + 1], w1, v);
                v = fmaf(g[i * 4 + 2], w2, v);
                v = fmaf(g[i * 4 + 3], w3, v);
                A_s[p ^ 1][cgrp8 + i][pix_g] = v;
            }
        }
        __syncthreads();
    }

    // ---- epilogue: coalesced float2 stores (512 B per wave per oc)
#pragma unroll
    for (int j = 0; j < 16; ++j) {
        float* op = out + ((size_t)b * COUT + wid * 16 + j) * HW
                        + h * WDIM + lane * 2;
        *(float2*)op = make_float2(acc[0][j], acc[1][j]);
    }
}

// ---------------------------------------------------------------------------
extern "C" void kernel_launch(void* const* d_in, const int* in_sizes, int n_in,
                              void* d_out, int out_size, void* d_ws, size_t ws_size,
                              hipStream_t stream)
{
    const float* x   = (const float*)d_in[0];
    const float* ow  = (const float*)d_in[1];
    const float* ob  = (const float*)d_in[2];
    const float* wgt = (const float*)d_in[3];
    float* out = (float*)d_out;

    // ws layout: py | px | Wt
    float* py = (float*)d_ws;
    float* px = py + (size_t)BATCH * KK * HW;
    float* wt = px + (size_t)BATCH * KK * HW;

    transpose_w_kernel<<<dim3((COUT * CIN * KK + 255) / 256), 256, 0, stream>>>(wgt, wt);

    offset_conv_kernel<<<dim3(1024), 256, 0, stream>>>(x, ow, ob, py, px);

    deform_main_kernel<<<dim3(BATCH * HDIM), 256, 0, stream>>>(x, wt, py, px, out);
}

// Round 5
// 355.796 us; speedup vs baseline: 1.2996x; 1.2996x over previous
//
#include <hip/hip_runtime.h>

#define BATCH 8
#define CIN   64
#define COUT  64
#define HDIM  128
#define WDIM  128
#define HW    (HDIM * WDIM)
#define KK    9
#define QC    8           // channels per pipeline step
#define NSTEP (KK * 8)    // 9 taps x 8 channel-groups = 72

// ---------------------------------------------------------------------------
// Kernel W: transpose weight [oc][c][k] -> Wt [k][c][oc]
// ---------------------------------------------------------------------------
__global__ __launch_bounds__(256) void transpose_w_kernel(
    const float* __restrict__ w, float* __restrict__ wt)
{
    const int i = blockIdx.x * 256 + threadIdx.x;   // 0 .. 64*64*9-1
    if (i < COUT * CIN * KK) {
        const int k = i / (CIN * COUT);
        const int r = i - k * (CIN * COUT);
        const int c = r >> 6;
        const int oc = r & 63;
        wt[i] = w[((size_t)oc * CIN + c) * KK + k];
    }
}

// ---------------------------------------------------------------------------
// Kernel A: offset conv, flattened grid, XCD-aligned batch (b = lin&7).
// ---------------------------------------------------------------------------
__global__ __launch_bounds__(256) void offset_conv_kernel(
    const float* __restrict__ x,
    const float* __restrict__ ow,   // [18][64][3][3]
    const float* __restrict__ ob,   // [18]
    float* __restrict__ py,         // [B][KK][HW]
    float* __restrict__ px)
{
    const int tid = threadIdx.x;
    const int lin = blockIdx.x;          // 0..1023
    const int b   = lin & 7;             // XCD-aligned batch
    const int par = (lin >> 3) & 1;      // 0: dy/py, 1: dx/px
    const int pixel = (lin >> 4) * 256 + tid;
    const int h = pixel >> 7;
    const int w = pixel & 127;

    float acc[9];
#pragma unroll
    for (int i = 0; i < 9; ++i) acc[i] = ob[2 * i + par];

    const float* xb = x + (size_t)b * CIN * HW;

    auto loadx = [&](float* xv, int c) {
        const float* xc = xb + c * HW;
#pragma unroll
        for (int dh = 0; dh < 3; ++dh) {
            const int y = h + dh - 1;
            const bool vy = (unsigned)y < (unsigned)HDIM;
#pragma unroll
            for (int dw = 0; dw < 3; ++dw) {
                const int xw = w + dw - 1;
                const bool vx = (unsigned)xw < (unsigned)WDIM;
                float v = 0.0f;
                if (vy && vx) v = xc[y * WDIM + xw];
                xv[dh * 3 + dw] = v;
            }
        }
    };

    float xva[9], xvb[9];
    loadx(xva, 0);
    for (int c = 0; c < CIN; c += 2) {
        loadx(xvb, c + 1);
#pragma unroll
        for (int i = 0; i < 9; ++i) {
            const float* wp = ow + ((size_t)(2 * i + par) * CIN + c) * 9;
#pragma unroll
            for (int t = 0; t < 9; ++t) acc[i] = fmaf(xva[t], wp[t], acc[i]);
        }
        if (c + 2 < CIN) loadx(xva, c + 2);
#pragma unroll
        for (int i = 0; i < 9; ++i) {
            const float* wp = ow + ((size_t)(2 * i + par) * CIN + (c + 1)) * 9;
#pragma unroll
            for (int t = 0; t < 9; ++t) acc[i] = fmaf(xvb[t], wp[t], acc[i]);
        }
    }

    float* dst = par ? px : py;
#pragma unroll
    for (int i = 0; i < 9; ++i) {
        const int ki = i / 3, kj = i % 3;
        const float base = par ? (float)(w - 1 + kj) : (float)(h - 1 + ki);
        dst[((size_t)b * KK + i) * HW + pixel] = base + acc[i];
    }
}

// ---------------------------------------------------------------------------
// Kernel B v5 == v3 geometry + XCD-aligned batch.
// Block = 512 threads (8 waves), 2 rows (256 px) x 64 oc; b = blk&7 so all
// blocks of batch b land on XCD b -> x gathers are L2-resident (4.2 MB/XCD).
// Wave w owns 8 oc; lane owns 4 px -> acc[4][8]. 72 steps of 8 channels.
// Per step: issue next group's 16 scattered gathers (in-flight regs) ->
// GEMM current group (s_load W, ds_read_b128 A) -> blend+LDS write -> barrier.
// ---------------------------------------------------------------------------
__global__ __launch_bounds__(512)
__attribute__((amdgpu_waves_per_eu(4, 4)))
void deform_main_kernel(
    const float* __restrict__ x,
    const float* __restrict__ wt,   // [k][c][oc]
    const float* __restrict__ py,
    const float* __restrict__ px,
    float* __restrict__ out)
{
    __shared__ float A_s[2][QC][256];   // 16 KB

    const int tid = threadIdx.x;
    const int blk = blockIdx.x;
    const int b  = blk & 7;              // XCD-aligned batch
    const int h0 = (blk >> 3) * 2;       // row pair
    const int lane = tid & 63;
    const int ocg = __builtin_amdgcn_readfirstlane(tid >> 6);  // uniform wave id
    const int pix_g = tid & 255;         // gather pixel (0..255, 2 rows)
    const int cgrp4 = (tid >> 8) * 4;    // 0 or 4: channel sub-group

    float acc[4][8];
#pragma unroll
    for (int i = 0; i < 4; ++i)
#pragma unroll
        for (int j = 0; j < 8; ++j) acc[i][j] = 0.0f;

    const char* xb = (const char*)(x + (size_t)b * CIN * HW);
    const float* pyb = py + (size_t)b * KK * HW + h0 * WDIM + pix_g;
    const float* pxb = px + (size_t)b * KK * HW + h0 * WDIM + pix_g;

    int   idb0, idb1, idb2, idb3;   // byte offsets of 4 bilinear corners
    float w0, w1, w2, w3;           // bilinear weights (validity folded in)
    auto compute_params = [&](float pyv_, float pxv_) {
        const float y0f = floorf(pyv_), x0f = floorf(pxv_);
        const float fy = pyv_ - y0f, fx = pxv_ - x0f;
        const int y0 = (int)y0f, x0 = (int)x0f;
        const int y1 = y0 + 1, x1 = x0 + 1;
        const bool vy0 = (unsigned)y0 < (unsigned)HDIM;
        const bool vy1 = (unsigned)y1 < (unsigned)HDIM;
        const bool vx0 = (unsigned)x0 < (unsigned)WDIM;
        const bool vx1 = (unsigned)x1 < (unsigned)WDIM;
        const int cy0 = min(max(y0, 0), HDIM - 1);
        const int cy1 = min(max(y1, 0), HDIM - 1);
        const int cx0 = min(max(x0, 0), WDIM - 1);
        const int cx1 = min(max(x1, 0), WDIM - 1);
        idb0 = (cy0 * WDIM + cx0) * 4;  idb1 = (cy0 * WDIM + cx1) * 4;
        idb2 = (cy1 * WDIM + cx0) * 4;  idb3 = (cy1 * WDIM + cx1) * 4;
        const float wy0 = 1.0f - fy, wy1 = fy;
        const float wx0 = 1.0f - fx, wx1 = fx;
        w0 = wy0 * wx0 * (float)(vy0 && vx0);
        w1 = wy0 * wx1 * (float)(vy0 && vx1);
        w2 = wy1 * wx0 * (float)(vy1 && vx0);
        w3 = wy1 * wx1 * (float)(vy1 && vx1);
    };

    // ---- prologue: stage tap 0, channel-group 0 into buffer 0
    float pyv = pyb[0], pxv = pxb[0];
    compute_params(pyv, pxv);
    {
#pragma unroll
        for (int i = 0; i < 4; ++i) {
            const char* xc = xb + (size_t)(cgrp4 + i) * (HW * 4);
            float v = *(const float*)(xc + idb0) * w0;
            v = fmaf(*(const float*)(xc + idb1), w1, v);
            v = fmaf(*(const float*)(xc + idb2), w2, v);
            v = fmaf(*(const float*)(xc + idb3), w3, v);
            A_s[0][cgrp4 + i][pix_g] = v;
        }
    }
    __syncthreads();

    // ---- main pipelined loop: 72 steps of 8 channels
    for (int s = 0; s < NSTEP; ++s) {
        const int p = s & 1;
        const int sn = s + 1;
        const int tn = sn >> 3, qn = sn & 7;
        const bool hn = sn < NSTEP;

        // issue next group's 16 scattered gather loads (stay in flight)
        float g[16];
        if (hn) {
            if (qn == 0) compute_params(pyv, pxv);  // params for tap tn
            const char* xq = xb + (size_t)(qn * QC + cgrp4) * (HW * 4);
#pragma unroll
            for (int i = 0; i < 4; ++i) {
                const char* xc = xq + (size_t)i * (HW * 4);
                g[i * 4 + 0] = *(const float*)(xc + idb0);
                g[i * 4 + 1] = *(const float*)(xc + idb1);
                g[i * 4 + 2] = *(const float*)(xc + idb2);
                g[i * 4 + 3] = *(const float*)(xc + idb3);
            }
            if (qn == 6 && tn + 1 < KK) {   // prefetch next tap's positions
                pyv = pyb[(size_t)(tn + 1) * HW];
                pxv = pxb[(size_t)(tn + 1) * HW];
            }
        }

        // GEMM on current group: A from LDS, W from scalar (uniform) loads
        {
            const int ks = s >> 3, qs = s & 7;
            const float* wq = wt + ((size_t)ks * CIN + qs * QC) * COUT + ocg * 8;
#pragma unroll
            for (int c = 0; c < QC; ++c) {
                const float4 a = *(const float4*)&A_s[p][c][lane * 4];
#pragma unroll
                for (int j = 0; j < 8; ++j) {
                    const float wv = wq[c * COUT + j];   // s_load (uniform)
                    acc[0][j] = fmaf(a.x, wv, acc[0][j]);
                    acc[1][j] = fmaf(a.y, wv, acc[1][j]);
                    acc[2][j] = fmaf(a.z, wv, acc[2][j]);
                    acc[3][j] = fmaf(a.w, wv, acc[3][j]);
                }
            }
        }

        // blend gathered values, write into the other buffer
        if (hn) {
#pragma unroll
            for (int i = 0; i < 4; ++i) {
                float v = g[i * 4 + 0] * w0;
                v = fmaf(g[i * 4 + 1], w1, v);
                v = fmaf(g[i * 4 + 2], w2, v);
                v = fmaf(g[i * 4 + 3], w3, v);
                A_s[p ^ 1][cgrp4 + i][pix_g] = v;
            }
        }
        __syncthreads();
    }

    // ---- epilogue: coalesced float4 stores
#pragma unroll
    for (int j = 0; j < 8; ++j) {
        float* op = out + ((size_t)b * COUT + ocg * 8 + j) * HW
                        + h0 * WDIM + lane * 4;
        *(float4*)op = make_float4(acc[0][j], acc[1][j], acc[2][j], acc[3][j]);
    }
}

// ---------------------------------------------------------------------------
extern "C" void kernel_launch(void* const* d_in, const int* in_sizes, int n_in,
                              void* d_out, int out_size, void* d_ws, size_t ws_size,
                              hipStream_t stream)
{
    const float* x   = (const float*)d_in[0];
    const float* ow  = (const float*)d_in[1];
    const float* ob  = (const float*)d_in[2];
    const float* wgt = (const float*)d_in[3];
    float* out = (float*)d_out;

    // ws layout: py | px | Wt
    float* py = (float*)d_ws;
    float* px = py + (size_t)BATCH * KK * HW;
    float* wt = px + (size_t)BATCH * KK * HW;

    transpose_w_kernel<<<dim3((COUT * CIN * KK + 255) / 256), 256, 0, stream>>>(wgt, wt);

    offset_conv_kernel<<<dim3(1024), 256, 0, stream>>>(x, ow, ob, py, px);

    deform_main_kernel<<<dim3(BATCH * HDIM / 2), 512, 0, stream>>>(x, wt, py, px, out);
}

// Round 6
// 304.739 us; speedup vs baseline: 1.5173x; 1.1675x over previous
//
#include <hip/hip_runtime.h>

#define BATCH 8
#define CIN   64
#define COUT  64
#define HDIM  128
#define WDIM  128
#define HW    (HDIM * WDIM)
#define KK    9

typedef __attribute__((ext_vector_type(8)))  short  short8v;
typedef __attribute__((ext_vector_type(8)))  __bf16 bf16x8;
typedef __attribute__((ext_vector_type(16))) float  f32x16;
typedef float __attribute__((ext_vector_type(2), aligned(4))) float2u;  // 4B-aligned pair load

__device__ __forceinline__ short f2bf(float f) {   // fp32 -> bf16 RNE
    unsigned u = __float_as_uint(f);
    return (short)((u + 0x7fffu + ((u >> 16) & 1u)) >> 16);
}
__device__ __forceinline__ float bf2f(short s) {
    return __uint_as_float(((unsigned)(unsigned short)s) << 16);
}
__device__ __forceinline__ f32x16 mfma_bf16(short8v a, short8v b, f32x16 c) {
    return __builtin_amdgcn_mfma_f32_32x32x16_bf16(
        __builtin_bit_cast(bf16x8, a), __builtin_bit_cast(bf16x8, b), c, 0, 0, 0);
}

// ---------------------------------------------------------------------------
// W prep: weight [oc][c][3][3] -> MFMA A-operand frags, split bf16 hi/lo.
// Frag (32x32x16, A=oc x c): lane l holds A[oc = l&31][c = ks*16+(l>>5)*8+e].
// Layout: Wf[((t*4+ks)*2+mt)*2 + pl][lane*8 + e]  (512 shorts per frag).
// ---------------------------------------------------------------------------
__global__ __launch_bounds__(64) void wprep_kernel(
    const float* __restrict__ w, short* __restrict__ Wf)
{
    const int l   = threadIdx.x;
    const int blk = blockIdx.x;          // (t*4+ks)*2+mt, 72 blocks
    const int mt  = blk & 1;
    const int ks  = (blk >> 1) & 3;
    const int t   = blk >> 3;
    const int oc  = mt * 32 + (l & 31);
    const int cb  = ks * 16 + (l >> 5) * 8;
    short* p0 = Wf + ((size_t)blk * 2 + 0) * 512 + l * 8;
    short* p1 = Wf + ((size_t)blk * 2 + 1) * 512 + l * 8;
#pragma unroll
    for (int e = 0; e < 8; ++e) {
        float v = w[((size_t)oc * CIN + (cb + e)) * KK + t];
        short h = f2bf(v);
        p0[e] = h;
        p1[e] = f2bf(v - bf2f(h));
    }
}

// ---------------------------------------------------------------------------
// Kernel A: offset conv (unchanged from R5): flattened grid, XCD-aligned b.
// ---------------------------------------------------------------------------
__global__ __launch_bounds__(256) void offset_conv_kernel(
    const float* __restrict__ x,
    const float* __restrict__ ow,   // [18][64][3][3]
    const float* __restrict__ ob,   // [18]
    float* __restrict__ py,         // [B][KK][HW]
    float* __restrict__ px)
{
    const int tid = threadIdx.x;
    const int lin = blockIdx.x;          // 0..1023
    const int b   = lin & 7;
    const int par = (lin >> 3) & 1;      // 0: dy/py, 1: dx/px
    const int pixel = (lin >> 4) * 256 + tid;
    const int h = pixel >> 7;
    const int w = pixel & 127;

    float acc[9];
#pragma unroll
    for (int i = 0; i < 9; ++i) acc[i] = ob[2 * i + par];

    const float* xb = x + (size_t)b * CIN * HW;

    auto loadx = [&](float* xv, int c) {
        const float* xc = xb + c * HW;
#pragma unroll
        for (int dh = 0; dh < 3; ++dh) {
            const int y = h + dh - 1;
            const bool vy = (unsigned)y < (unsigned)HDIM;
#pragma unroll
            for (int dw = 0; dw < 3; ++dw) {
                const int xw = w + dw - 1;
                const bool vx = (unsigned)xw < (unsigned)WDIM;
                float v = 0.0f;
                if (vy && vx) v = xc[y * WDIM + xw];
                xv[dh * 3 + dw] = v;
            }
        }
    };

    float xva[9], xvb[9];
    loadx(xva, 0);
    for (int c = 0; c < CIN; c += 2) {
        loadx(xvb, c + 1);
#pragma unroll
        for (int i = 0; i < 9; ++i) {
            const float* wp = ow + ((size_t)(2 * i + par) * CIN + c) * 9;
#pragma unroll
            for (int t = 0; t < 9; ++t) acc[i] = fmaf(xva[t], wp[t], acc[i]);
        }
        if (c + 2 < CIN) loadx(xva, c + 2);
#pragma unroll
        for (int i = 0; i < 9; ++i) {
            const float* wp = ow + ((size_t)(2 * i + par) * CIN + (c + 1)) * 9;
#pragma unroll
            for (int t = 0; t < 9; ++t) acc[i] = fmaf(xvb[t], wp[t], acc[i]);
        }
    }

    float* dst = par ? px : py;
#pragma unroll
    for (int i = 0; i < 9; ++i) {
        const int ki = i / 3, kj = i % 3;
        const float base = par ? (float)(w - 1 + kj) : (float)(h - 1 + ki);
        dst[((size_t)b * KK + i) * HW + pixel] = base + acc[i];
    }
}

// ---------------------------------------------------------------------------
// Kernel B v6: deformable sampling + split-bf16 MFMA implicit GEMM.
// Grid 1024 (b=blk&7 XCD-aligned, h=blk>>3); 256 threads = 4 waves.
// GEMM: D[oc=64][px=128] += W[oc,K] * A[K,px], K = 576 = 9 taps x 4 Ksteps(16c).
// Wave w = px N-tile [32w,32w+32); acc = 2 M-tiles (oc 0-31, 32-63) f32x16.
// Per Kstep: blend+pack prev gathers -> A_s (bf16 hi/lo, 80B/px padded rows),
// issue next Kstep's paired dwordx2 gathers (2/value via x-adjacency, clamp
// cases folded into per-(px,tap) adjusted weights), barrier, 6 MFMA.
// ---------------------------------------------------------------------------
__global__ __launch_bounds__(256)
__attribute__((amdgpu_waves_per_eu(4, 4)))
void deform_mfma_kernel(
    const float* __restrict__ x,
    const short* __restrict__ Wf,
    const float* __restrict__ py,
    const float* __restrict__ px_,
    float* __restrict__ out)
{
    __shared__ int A_s[2][128 * 20];   // [buf][px*20 + pl*8 + q*4] ints, 20 KB

    const int tid = threadIdx.x;
    const int blk = blockIdx.x;
    const int b  = blk & 7;            // XCD-aligned batch
    const int h  = blk >> 3;           // row
    const int l  = tid & 63;
    const int wv = tid >> 6;           // wave id = px N-tile
    const int pxg = tid & 127;         // sampler pixel
    const int ch  = tid >> 7;          // c-half (0/1) within 16c Kstep

    f32x16 acc0, acc1;
#pragma unroll
    for (int i = 0; i < 16; ++i) { acc0[i] = 0.f; acc1[i] = 0.f; }

    const char* xb = (const char*)(x + (size_t)b * CIN * HW);
    const float* pyb = py  + (size_t)b * KK * HW + h * WDIM + pxg;
    const float* pxb = px_ + (size_t)b * KK * HW + h * WDIM + pxg;

    int ob0, ob1;                       // byte offsets of the two row-pair loads
    float a0, b0c, a2, b2c;             // adjusted bilinear weights
    auto cparams = [&](float pv, float qv) {
        const float y0f = floorf(pv), x0f = floorf(qv);
        const float fy = pv - y0f, fx = qv - x0f;
        const int y0 = (int)y0f, x0 = (int)x0f;
        const bool vy0 = (unsigned)y0 < (unsigned)HDIM;
        const bool vy1 = (unsigned)(y0 + 1) < (unsigned)HDIM;
        const bool vx0 = (unsigned)x0 < (unsigned)WDIM;
        const bool vx1 = (unsigned)(x0 + 1) < (unsigned)WDIM;
        const int cy0 = min(max(y0, 0), HDIM - 1);
        const int cy1 = min(max(y0 + 1, 0), HDIM - 1);
        const int axc = min(max(x0, 0), WDIM - 2);   // pair load at (cy, axc..axc+1)
        ob0 = (cy0 * WDIM + axc) * 4;
        ob1 = (cy1 * WDIM + axc) * 4;
        const float wxL = vx0 ? (1.f - fx) : 0.f;
        const float wxR = vx1 ? fx : 0.f;
        float cgx, cgy;                 // coefs on pair .x / .y (clamp-folded)
        if (x0 < 0)               { cgx = wxR; cgy = 0.f; }
        else if (x0 >= WDIM - 1)  { cgx = 0.f; cgy = wxL; }
        else                      { cgx = wxL; cgy = wxR; }
        const float wy0v = vy0 ? (1.f - fy) : 0.f;
        const float wy1v = vy1 ? fy : 0.f;
        a0 = wy0v * cgx; b0c = wy0v * cgy;
        a2 = wy1v * cgx; b2c = wy1v * cgy;
    };

    float2u gA[8], gB[8];
    auto issue = [&](int cbase) {       // 16 paired gathers for one 8c half
#pragma unroll
        for (int i = 0; i < 8; ++i) {
            const char* xc = xb + (size_t)(cbase + i) * (HW * 4);
            gA[i] = *(const float2u*)(xc + ob0);
            gB[i] = *(const float2u*)(xc + ob1);
        }
    };
    auto blendwrite = [&](int buf) {    // blend 8 values, split bf16, -> LDS
        int* dst = &A_s[buf][pxg * 20 + ch * 4];
        int hi_d[4], lo_d[4];
#pragma unroll
        for (int p = 0; p < 4; ++p) {
            float v0 = gA[2*p].x * a0;
            v0 = fmaf(gA[2*p].y, b0c, v0);
            v0 = fmaf(gB[2*p].x, a2,  v0);
            v0 = fmaf(gB[2*p].y, b2c, v0);
            float v1 = gA[2*p+1].x * a0;
            v1 = fmaf(gA[2*p+1].y, b0c, v1);
            v1 = fmaf(gB[2*p+1].x, a2,  v1);
            v1 = fmaf(gB[2*p+1].y, b2c, v1);
            const short h0 = f2bf(v0), h1 = f2bf(v1);
            hi_d[p] = ((int)(unsigned short)h0) | (((int)(unsigned short)h1) << 16);
            const short l0 = f2bf(v0 - bf2f(h0)), l1 = f2bf(v1 - bf2f(h1));
            lo_d[p] = ((int)(unsigned short)l0) | (((int)(unsigned short)l1) << 16);
        }
        *(int4*)dst       = make_int4(hi_d[0], hi_d[1], hi_d[2], hi_d[3]);
        *(int4*)(dst + 8) = make_int4(lo_d[0], lo_d[1], lo_d[2], lo_d[3]);
    };

    // ---- prologue: params tap0, gathers Kstep0, prefetch tap1 positions
    float pyv = pyb[0], pxv = pxb[0];
    cparams(pyv, pxv);
    issue(ch * 8);
    if (KK > 1) { pyv = pyb[HW]; pxv = pxb[HW]; }

    // ---- main loop: 36 Ksteps (9 taps x 4)
    for (int s = 0; s < 36; ++s) {
        const int buf = s & 1;
        blendwrite(buf);

        const int sn = s + 1;
        if (sn < 36) {
            if ((sn & 3) == 0) {            // new tap
                cparams(pyv, pxv);
                const int tn = (sn >> 2) + 1;
                if (tn < KK) { pyv = pyb[(size_t)tn * HW]; pxv = pxb[(size_t)tn * HW]; }
            }
            issue((sn & 3) * 16 + ch * 8);  // overlap latency with barrier+MFMA
        }
        __syncthreads();

        // MFMA: W frags (global, L2-hot) x A frags (LDS), 3 split products
        const short* wf = Wf + (size_t)((s * 2) * 2) * 512;   // (tap*4+ks)*2*2*512
        const short8v w0h = *(const short8v*)(wf + 0 * 512 + l * 8);
        const short8v w0l = *(const short8v*)(wf + 1 * 512 + l * 8);
        const short8v w1h = *(const short8v*)(wf + 2 * 512 + l * 8);
        const short8v w1l = *(const short8v*)(wf + 3 * 512 + l * 8);
        const int aoff = (32 * wv + (l & 31)) * 20 + (l >> 5) * 4;
        const short8v bh = *(const short8v*)&A_s[buf][aoff];
        const short8v bl = *(const short8v*)&A_s[buf][aoff + 8];
        acc0 = mfma_bf16(w0h, bh, acc0);
        acc1 = mfma_bf16(w1h, bh, acc1);
        acc0 = mfma_bf16(w0l, bh, acc0);
        acc1 = mfma_bf16(w1l, bh, acc1);
        acc0 = mfma_bf16(w0h, bl, acc0);
        acc1 = mfma_bf16(w1h, bl, acc1);
    }

    // ---- epilogue: C/D layout col=lane&31 (px), row=(r&3)+8*(r>>2)+4*(l>>5)
    float* ob = out + (size_t)b * COUT * HW + h * WDIM + 32 * wv + (l & 31);
#pragma unroll
    for (int r = 0; r < 16; ++r) {
        const int oc0 = (r & 3) + 8 * (r >> 2) + 4 * (l >> 5);
        ob[(size_t)oc0 * HW]        = acc0[r];
        ob[(size_t)(oc0 + 32) * HW] = acc1[r];
    }
}

// ---------------------------------------------------------------------------
extern "C" void kernel_launch(void* const* d_in, const int* in_sizes, int n_in,
                              void* d_out, int out_size, void* d_ws, size_t ws_size,
                              hipStream_t stream)
{
    const float* x   = (const float*)d_in[0];
    const float* ow  = (const float*)d_in[1];
    const float* obi = (const float*)d_in[2];
    const float* wgt = (const float*)d_in[3];
    float* out = (float*)d_out;

    // ws layout: py | px | Wf (bf16 frags)
    float* pyw = (float*)d_ws;
    float* pxw = pyw + (size_t)BATCH * KK * HW;
    short* Wf  = (short*)(pxw + (size_t)BATCH * KK * HW);

    wprep_kernel<<<dim3(72), 64, 0, stream>>>(wgt, Wf);
    offset_conv_kernel<<<dim3(1024), 256, 0, stream>>>(x, ow, obi, pyw, pxw);
    deform_mfma_kernel<<<dim3(1024), 256, 0, stream>>>(x, Wf, pyw, pxw, out);
}

// Round 8
// 213.944 us; speedup vs baseline: 2.1612x; 1.4244x over previous
//
#include <hip/hip_runtime.h>

#define BATCH 8
#define CIN   64
#define COUT  64
#define HDIM  128
#define WDIM  128
#define HW    (HDIM * WDIM)
#define KK    9

typedef __attribute__((ext_vector_type(8)))  short  short8v;
typedef __attribute__((ext_vector_type(8)))  __bf16 bf16x8;
typedef __attribute__((ext_vector_type(16))) float  f32x16;
typedef float __attribute__((ext_vector_type(2), aligned(4))) float2u;

__device__ __forceinline__ short f2bf(float f) {   // fp32 -> bf16 RNE
    unsigned u = __float_as_uint(f);
    return (short)((u + 0x7fffu + ((u >> 16) & 1u)) >> 16);
}
__device__ __forceinline__ float bf2f(short s) {
    return __uint_as_float(((unsigned)(unsigned short)s) << 16);
}
__device__ __forceinline__ f32x16 mfma_bf16(short8v a, short8v b, f32x16 c) {
    return __builtin_amdgcn_mfma_f32_32x32x16_bf16(
        __builtin_bit_cast(bf16x8, a), __builtin_bit_cast(bf16x8, b), c, 0, 0, 0);
}

// ---------------------------------------------------------------------------
// W prep: weight [oc][c][3][3] -> MFMA A-operand frags, split bf16 hi/lo.
// K-order: s = cg*9 + t (c-group major, tap minor). blk = s*2 + mt.
// Lane l holds A[oc = mt*32+(l&31)][c = cg*16+(l>>5)*8+e].
// ---------------------------------------------------------------------------
__global__ __launch_bounds__(64) void wprep_kernel(
    const float* __restrict__ w, short* __restrict__ Wf)
{
    const int l   = threadIdx.x;
    const int blk = blockIdx.x;          // 0..71
    const int mt  = blk & 1;
    const int s   = blk >> 1;            // 0..35
    const int cg  = s / 9;
    const int t   = s - cg * 9;
    const int oc  = mt * 32 + (l & 31);
    const int cb  = cg * 16 + (l >> 5) * 8;
    short* p0 = Wf + ((size_t)blk * 2 + 0) * 512 + l * 8;
    short* p1 = Wf + ((size_t)blk * 2 + 1) * 512 + l * 8;
#pragma unroll
    for (int e = 0; e < 8; ++e) {
        float v = w[((size_t)oc * CIN + (cb + e)) * KK + t];
        short h = f2bf(v);
        p0[e] = h;
        p1[e] = f2bf(v - bf2f(h));
    }
}

// ---------------------------------------------------------------------------
// Kernel A v3 (audited, unchanged from R7): offset conv, LDS row-staged.
// ---------------------------------------------------------------------------
__global__ __launch_bounds__(256) void offset_conv_kernel(
    const float* __restrict__ x,
    const float* __restrict__ ow,   // [18][64][3][3]
    const float* __restrict__ ob,   // [18]
    float* __restrict__ py,         // [B][KK][HW]
    float* __restrict__ px)
{
    __shared__ float Xs[2][4][132];     // 4 rows x cols [-1..130], halo zeroed

    const int tid = threadIdx.x;
    const int lin = blockIdx.x;          // 0..1023
    const int b   = lin & 7;             // XCD-aligned batch
    const int par = (lin >> 3) & 1;
    const int pg  = lin >> 4;            // 0..63
    const int h0  = pg * 2;
    const int hh  = tid >> 7;            // 0/1: row within pair
    const int w   = tid & 127;

    if (tid < 16) {
        const int bu = tid >> 3, r = (tid >> 1) & 3, side = tid & 1;
        Xs[bu][r][1 + side * 129] = 0.0f;
    }

    float acc[9];
#pragma unroll
    for (int i = 0; i < 9; ++i) acc[i] = ob[2 * i + par];

    const float* xb = x + (size_t)b * CIN * HW;

    const int st_r   = tid >> 6;
    const int st_col = (tid * 2) & 127;
    const int st_y   = h0 - 1 + st_r;
    const bool st_v  = (unsigned)st_y < (unsigned)HDIM;
    const float* st_src = xb + (size_t)st_y * WDIM + st_col;

    float2 ld;
    auto issue = [&](int c) {
        ld = st_v ? *(const float2*)(st_src + (size_t)c * HW)
                  : make_float2(0.0f, 0.0f);
    };
    auto write = [&](int bu) {
        *(float2*)&Xs[bu][st_r][2 + st_col] = ld;
    };

    issue(0);
    write(0);
    __syncthreads();

    for (int c = 0; c < CIN; ++c) {
        const int bu = c & 1;
        if (c + 1 < CIN) issue(c + 1);

        float tv[9];
#pragma unroll
        for (int di = 0; di < 3; ++di)
#pragma unroll
            for (int dj = 0; dj < 3; ++dj)
                tv[di * 3 + dj] = Xs[bu][hh + di][w + dj + 1];

        const float* wb = ow + (size_t)par * (CIN * 9) + c * 9;
#pragma unroll
        for (int i = 0; i < 9; ++i) {
            const float* wp = wb + (size_t)i * (2 * CIN * 9);  // oc = 2i+par
#pragma unroll
            for (int t = 0; t < 9; ++t) acc[i] = fmaf(tv[t], wp[t], acc[i]);
        }

        if (c + 1 < CIN) write(bu ^ 1);
        __syncthreads();
    }

    const int pixel = pg * 256 + tid;
    float* dst = par ? px : py;
#pragma unroll
    for (int i = 0; i < 9; ++i) {
        const int ki = i / 3, kj = i % 3;
        const float base = par ? (float)(w - 1 + kj) : (float)((h0 + hh) - 1 + ki);
        dst[((size_t)b * KK + i) * HW + pixel] = base + acc[i];
    }
}

// ---------------------------------------------------------------------------
// Kernel B v8: in-register sampling from an 8-row LDS window + MFMA.
// Grid 1024 (b=blk&7 XCD-pinned, h=blk>>3); 256 thr = 4 waves.
// Window: rows [h-3, h+4] x 16 channels fp32 (64 KB), staged per c-group.
// Each lane samples ITS OWN B-fragment (pixel 32wv+(l&31), channels
// (l>>5)*8+e) straight from the window into registers -> no A_s LDS, no
// per-tap barrier (only 2 per c-group). Safety: per-lane fallback to global
// gather if a sample leaves the window (oob; statistically never).
// ---------------------------------------------------------------------------
__global__ __launch_bounds__(256)
__attribute__((amdgpu_waves_per_eu(2, 4)))
void deform_mfma_kernel(
    const float* __restrict__ x,
    const short* __restrict__ Wf,
    const float* __restrict__ py,
    const float* __restrict__ px_,
    float* __restrict__ out)
{
    __shared__ float Xw[8][16][128];     // 64 KB fp32 sampling window

    const int tid = threadIdx.x;
    const int blk = blockIdx.x;
    const int b  = blk & 7;              // XCD-aligned batch
    const int h  = blk >> 3;             // output row
    const int l  = tid & 63;
    const int wv = tid >> 6;             // wave id = px N-tile
    const int mypx = 32 * wv + (l & 31); // this lane's pixel
    const int ch8  = (l >> 5) * 8;       // this lane's channel sub-base

    f32x16 acc0, acc1;
#pragma unroll
    for (int i = 0; i < 16; ++i) { acc0[i] = 0.f; acc1[i] = 0.f; }

    const float* xb = x + (size_t)b * CIN * HW;
    const float* pyb = py  + (size_t)b * KK * HW + h * WDIM + mypx;
    const float* pxb = px_ + (size_t)b * KK * HW + h * WDIM + mypx;

    // stage c-group cg: 16 float4 per thread, coalesced, zero OOB rows
    auto stage = [&](int cg) {
#pragma unroll
        for (int i = 0; i < 16; ++i) {
            const int f = i * 256 + tid;        // float4 idx over [8][16][32]
            const int r   = f >> 9;             // 0..7
            const int c   = (f >> 5) & 15;
            const int col = (f & 31) * 4;
            const int y = h - 3 + r;
            float4 v = make_float4(0.f, 0.f, 0.f, 0.f);
            if ((unsigned)y < (unsigned)HDIM)
                v = *(const float4*)(xb + (size_t)(cg * 16 + c) * HW + y * WDIM + col);
            *(float4*)&Xw[r][c][col] = v;
        }
    };

    float pyc = pyb[0], pxc = pxb[0];    // tap-0 positions

    for (int cg = 0; cg < 4; ++cg) {
        __syncthreads();                 // prev window fully consumed
        stage(cg);
        __syncthreads();

        for (int t = 0; t < 9; ++t) {
            const int s = cg * 9 + t;

            // W frags for this K-step (global, L2-hot) — issue early
            const short* wf = Wf + (size_t)(s * 4) * 512;
            const short8v w0h = *(const short8v*)(wf + 0 * 512 + l * 8);
            const short8v w0l = *(const short8v*)(wf + 1 * 512 + l * 8);
            const short8v w1h = *(const short8v*)(wf + 2 * 512 + l * 8);
            const short8v w1l = *(const short8v*)(wf + 3 * 512 + l * 8);

            // ---- sampling params for this lane's pixel
            const float y0f = floorf(pyc), x0f = floorf(pxc);
            const float fy = pyc - y0f, fx = pxc - x0f;
            const int y0 = (int)y0f, x0 = (int)x0f;
            const bool vy0 = (unsigned)y0 < (unsigned)HDIM;
            const bool vy1 = (unsigned)(y0 + 1) < (unsigned)HDIM;
            const bool vx0 = (unsigned)x0 < (unsigned)WDIM;
            const bool vx1 = (unsigned)(x0 + 1) < (unsigned)WDIM;
            const int cy0 = min(max(y0, 0), HDIM - 1);
            const int cy1 = min(max(y0 + 1, 0), HDIM - 1);
            const int axc = min(max(x0, 0), WDIM - 2);
            const float wxL = vx0 ? (1.f - fx) : 0.f;
            const float wxR = vx1 ? fx : 0.f;
            float cgx, cgy;
            if (x0 < 0)              { cgx = wxR; cgy = 0.f; }
            else if (x0 >= WDIM - 1) { cgx = 0.f; cgy = wxL; }
            else                     { cgx = wxL; cgy = wxR; }
            const float wy0v = vy0 ? (1.f - fy) : 0.f;
            const float wy1v = vy1 ? fy : 0.f;
            const float a0  = wy0v * cgx, b0c = wy0v * cgy;
            const float a2  = wy1v * cgx, b2c = wy1v * cgy;

            // prefetch next tap's positions (independent of this tap's work)
            const int t2 = (t + 1) % 9;
            pyc = pyb[(size_t)t2 * HW];
            pxc = pxb[(size_t)t2 * HW];

            const int r0 = cy0 - (h - 3), r1 = cy1 - (h - 3);
            const bool oob = ((unsigned)r0 > 7u) | ((unsigned)r1 > 7u);

            // ---- sample this lane's 8 channels
            float v[8];
            if (!oob) {
#pragma unroll
                for (int e = 0; e < 8; ++e) {
                    const float2u p0 = *(const float2u*)&Xw[r0][ch8 + e][axc];
                    const float2u p1 = *(const float2u*)&Xw[r1][ch8 + e][axc];
                    float s0 = p0.x * a0;
                    s0 = fmaf(p0.y, b0c, s0);
                    s0 = fmaf(p1.x, a2,  s0);
                    s0 = fmaf(p1.y, b2c, s0);
                    v[e] = s0;
                }
            } else {                         // statistically-never global path
                const int cbase = cg * 16 + ch8;
#pragma unroll
                for (int e = 0; e < 8; ++e) {
                    const float* xc = xb + (size_t)(cbase + e) * HW;
                    float s0 = xc[cy0 * WDIM + axc] * a0;
                    s0 = fmaf(xc[cy0 * WDIM + axc + 1], b0c, s0);
                    s0 = fmaf(xc[cy1 * WDIM + axc],     a2,  s0);
                    s0 = fmaf(xc[cy1 * WDIM + axc + 1], b2c, s0);
                    v[e] = s0;
                }
            }

            // ---- split bf16 hi/lo, pack to fragments
            short8v bh, bl;
#pragma unroll
            for (int e = 0; e < 8; ++e) {
                const short hs = f2bf(v[e]);
                bh[e] = hs;
                bl[e] = f2bf(v[e] - bf2f(hs));
            }

            acc0 = mfma_bf16(w0h, bh, acc0);
            acc1 = mfma_bf16(w1h, bh, acc1);
            acc0 = mfma_bf16(w0l, bh, acc0);
            acc1 = mfma_bf16(w1l, bh, acc1);
            acc0 = mfma_bf16(w0h, bl, acc0);
            acc1 = mfma_bf16(w1h, bl, acc1);
        }
    }

    // ---- epilogue: C/D layout col=lane&31 (px), row=(r&3)+8*(r>>2)+4*(l>>5)
    float* ob = out + (size_t)b * COUT * HW + h * WDIM + 32 * wv + (l & 31);
#pragma unroll
    for (int r = 0; r < 16; ++r) {
        const int oc0 = (r & 3) + 8 * (r >> 2) + 4 * (l >> 5);
        ob[(size_t)oc0 * HW]        = acc0[r];
        ob[(size_t)(oc0 + 32) * HW] = acc1[r];
    }
}

// ---------------------------------------------------------------------------
extern "C" void kernel_launch(void* const* d_in, const int* in_sizes, int n_in,
                              void* d_out, int out_size, void* d_ws, size_t ws_size,
                              hipStream_t stream)
{
    const float* x   = (const float*)d_in[0];
    const float* ow  = (const float*)d_in[1];
    const float* obi = (const float*)d_in[2];
    const float* wgt = (const float*)d_in[3];
    float* out = (float*)d_out;

    // ws layout: py | px | Wf (bf16 frags)
    float* pyw = (float*)d_ws;
    float* pxw = pyw + (size_t)BATCH * KK * HW;
    short* Wf  = (short*)(pxw + (size_t)BATCH * KK * HW);

    wprep_kernel<<<dim3(72), 64, 0, stream>>>(wgt, Wf);
    offset_conv_kernel<<<dim3(1024), 256, 0, stream>>>(x, ow, obi, pyw, pxw);
    deform_mfma_kernel<<<dim3(1024), 256, 0, stream>>>(x, Wf, pyw, pxw, out);
}